// Round 1
// 202.572 us; speedup vs baseline: 1.0076x; 1.0076x over previous
//
#include <hip/hip_runtime.h>

typedef __bf16 bf16;
typedef __bf16 bf16x4 __attribute__((ext_vector_type(4)));
typedef __bf16 bf16x8 __attribute__((ext_vector_type(8)));
typedef float f32x4 __attribute__((ext_vector_type(4)));

// B_Nq = B_Ns = 16, C = 512, P = 1024, TAU*C = 256. I/O fp32; GEMMs bf16 MFMA.

#define GLL16(g, l)                                                             \
    __builtin_amdgcn_global_load_lds((const __attribute__((address_space(1))) void*)(g), \
                                     (__attribute__((address_space(3))) void*)(l), 16, 0, 0)

__device__ inline float wave_reduce_sum(float v) {
#pragma unroll
    for (int m = 32; m >= 1; m >>= 1) v += __shfl_xor(v, m, 64);
    return v;
}
__device__ inline float wave_reduce_max(float v) {
#pragma unroll
    for (int m = 32; m >= 1; m >>= 1) v = fmaxf(v, __shfl_xor(v, m, 64));
    return v;
}

// K0: fused prep — fs_mean (fp32+bf16), fs_mean transpose (bf16), f_q cvt to bf16.
// grid (32 p-tiles, 16 c-tiles), block 256.
__global__ void k_prep(const float* __restrict__ fs, const float* __restrict__ fq,
                       float* __restrict__ fsm32, bf16* __restrict__ fsm16,
                       bf16* __restrict__ fsmT, bf16* __restrict__ fq16) {
    __shared__ bf16 tile[32][33];
    int bx = blockIdx.x, by = blockIdx.y;
    int p0 = bx * 32, c0 = by * 32;
    int t = threadIdx.x, tx = t & 31, ty = t >> 5;
#pragma unroll
    for (int i = 0; i < 4; ++i) {
        size_t off = (size_t)(c0 + ty + 8 * i) * 1024 + p0 + tx;
        float s = 0.f;
#pragma unroll
        for (int b = 0; b < 16; ++b) s += fs[(size_t)b * 524288 + off];
        s *= (1.f / 16.f);
        fsm32[off] = s;
        bf16 h = (bf16)s;
        fsm16[off] = h;
        tile[ty + 8 * i][tx] = h;
    }
    __syncthreads();
#pragma unroll
    for (int i = 0; i < 4; ++i)
        fsmT[(size_t)(p0 + ty + 8 * i) * 512 + c0 + tx] = tile[tx][ty + 8 * i];
    // f_q fp32 -> bf16, 16384 floats per block
    int blk = by * 32 + bx;
    const float4* f4 = (const float4*)fq;
#pragma unroll
    for (int i = 0; i < 16; ++i) {
        int idx = blk * 4096 + i * 256 + t;  // float4 index
        float4 v = f4[idx];
        bf16x4 h4 = {(bf16)v.x, (bf16)v.y, (bf16)v.z, (bf16)v.w};
        *(bf16x4*)(fq16 + (size_t)idx * 4) = h4;
    }
}

// K1: rm[c] = rowmean(fs_mean[c,:]); u[c] = wsq[c]*wsk[c]*rm[c]/256
__global__ void k_u(const float* __restrict__ fsm32, const float* __restrict__ wsq,
                    const float* __restrict__ wsk, float* __restrict__ u,
                    float* __restrict__ rm) {
    int c = blockIdx.x;
    int t = threadIdx.x;
    float s = 0.f;
#pragma unroll
    for (int j = 0; j < 4; ++j) s += fsm32[(size_t)c * 1024 + t + 256 * j];
    s = wave_reduce_sum(s);
    __shared__ float red[4];
    int w = t >> 6, lane = t & 63;
    if (lane == 0) red[w] = s;
    __syncthreads();
    if (t == 0) {
        float rmv = (red[0] + red[1] + red[2] + red[3]) * (1.f / 1024.f);
        rm[c] = rmv;
        u[c] = wsq[c] * wsk[c] * rmv * (1.f / 256.f);
    }
}

// K2: G[b,c,d] = sum_p fq16[b,c,p]*fsm16[d,p] — 64(c)x128(d) LDS tile, K=1024.
// Wave retile: each wave 32 rows x 64 cols (2 m-tiles x 4 n-tiles) -> 6 ds_reads / 8 MFMAs.
// LDS XOR-swizzle (chunk ^= (row>>1)&3) applied via pre-swizzled global source
// (global_load_lds writes linearly) + same swizzle on ds_read -> bank-conflict-free.
// grid (4 dt, 8 ct, 16 b), 2 blocks/CU.
__global__ void k_gemm1(const bf16* __restrict__ A, const bf16* __restrict__ B,
                        float* __restrict__ G) {
    __shared__ alignas(16) bf16 As[64 * 32];
    __shared__ alignas(16) bf16 Bs[128 * 32];
    const int dt = blockIdx.x, ct = blockIdx.y, b = blockIdx.z;
    const int t = threadIdx.x, w = t >> 6, lane = t & 63;
    const int quad = lane >> 4, r15 = lane & 15;
    const int wr = w & 1, wc = w >> 1;
    const bf16* Abase = A + ((size_t)(b * 512 + ct * 64)) * 1024;
    const bf16* Bbase = B + ((size_t)(dt * 128)) * 1024;
    const int pr = t >> 2;                       // staged row (A: 0..63, B: two rows)
    const int gc = (t & 3) ^ ((pr >> 1) & 3);    // pre-swizzled global 16B-chunk
    f32x4 acc[2][4] = {};
    for (int k0 = 0; k0 < 1024; k0 += 32) {
        GLL16(Abase + (size_t)pr * 1024 + k0 + gc * 8, As + t * 8);
        GLL16(Bbase + (size_t)pr * 1024 + k0 + gc * 8, Bs + t * 8);
        GLL16(Bbase + (size_t)(pr + 64) * 1024 + k0 + gc * 8, Bs + (t + 256) * 8);
        __syncthreads();
        bf16x8 af[2], bfr[4];
#pragma unroll
        for (int mi = 0; mi < 2; ++mi) {
            int R = wr * 32 + mi * 16 + r15;
            int sc = quad ^ ((R >> 1) & 3);
            af[mi] = *(const bf16x8*)(As + R * 32 + sc * 8);
        }
#pragma unroll
        for (int j = 0; j < 4; ++j) {
            int R = wc * 64 + j * 16 + r15;
            int sc = quad ^ ((R >> 1) & 3);
            bfr[j] = *(const bf16x8*)(Bs + R * 32 + sc * 8);
        }
#pragma unroll
        for (int mi = 0; mi < 2; ++mi)
#pragma unroll
            for (int j = 0; j < 4; ++j)
                acc[mi][j] = __builtin_amdgcn_mfma_f32_16x16x32_bf16(af[mi], bfr[j], acc[mi][j], 0, 0, 0);
        __syncthreads();
    }
#pragma unroll
    for (int mi = 0; mi < 2; ++mi) {
        float* g = G + ((size_t)(b * 512 + ct * 64 + wr * 32 + mi * 16 + quad * 4)) * 512 +
                   dt * 128 + wc * 64 + r15;
#pragma unroll
        for (int j = 0; j < 4; ++j)
#pragma unroll
            for (int ii = 0; ii < 4; ++ii)
                g[(size_t)ii * 512 + j * 16] = acc[mi][j][ii];
    }
}

// K3: row softmax of G*wq[c]*wk[d]/P -> Acw (folds wv); r[b,c] = sum_d Acw*rm[d]
__global__ void k_softmax_ac(const float* __restrict__ G, const float* __restrict__ wq,
                             const float* __restrict__ wk, const float* __restrict__ wv,
                             const float* __restrict__ rm, bf16* __restrict__ Acw,
                             float* __restrict__ r) {
    int row = blockIdx.x * 4 + (threadIdx.x >> 6);  // b*512 + c
    int lane = threadIdx.x & 63;
    int c = row & 511;
    const float* g = G + (size_t)row * 512;
    float sc = wq[c] * (1.f / 1024.f);
    float v[8];
    float mx = -3.4e38f;
#pragma unroll
    for (int j = 0; j < 8; ++j) {
        int d = lane + 64 * j;
        v[j] = g[d] * sc * wk[d];
        mx = fmaxf(mx, v[j]);
    }
    mx = wave_reduce_max(mx);
    float sum = 0.f;
#pragma unroll
    for (int j = 0; j < 8; ++j) {
        v[j] = __expf(v[j] - mx);
        sum += v[j];
    }
    sum = wave_reduce_sum(sum);
    float inv = 1.f / sum;
    bf16* o = Acw + (size_t)row * 512;
    float rsum = 0.f;
#pragma unroll
    for (int j = 0; j < 8; ++j) {
        int d = lane + 64 * j;
        float aw = v[j] * inv * wv[d];
        o[d] = (bf16)aw;
        rsum += aw * rm[d];
    }
    rsum = wave_reduce_sum(rsum);
    if (lane == 0) r[row] = rsum;
}

// K4: tbp[half,b,d] = sum_{c in half} u[c]*Acw[b,c,d]   (grid (2,16,2))
// 4 partial sums to break the serial fp32 dependency chain.
__global__ void k_t(const bf16* __restrict__ Acw, const float* __restrict__ u,
                    float* __restrict__ tbp) {
    int half = blockIdx.z, b = blockIdx.y;
    int d = blockIdx.x * 256 + threadIdx.x;
    const bf16* base = Acw + (size_t)b * 262144 + (size_t)half * 256 * 512 + d;
    const float* uu = u + half * 256;
    float s0 = 0.f, s1 = 0.f, s2 = 0.f, s3 = 0.f;
#pragma unroll 4
    for (int c = 0; c < 256; c += 4) {
        s0 += uu[c] * (float)base[(size_t)c * 512];
        s1 += uu[c + 1] * (float)base[(size_t)(c + 1) * 512];
        s2 += uu[c + 2] * (float)base[(size_t)(c + 2) * 512];
        s3 += uu[c + 3] * (float)base[(size_t)(c + 3) * 512];
    }
    tbp[(half * 16 + b) * 512 + d] = (s0 + s1) + (s2 + s3);
}

// K5: out[b,c,p] = fq + lam*sum_d Acw[b,c,d]*fsmT[p,d] — 64(c)x128(p) tile, K=512.
// Same wave retile + LDS swizzle as K2. grid (8 pt, 8 ct, 16 b), 4 blocks/CU.
__global__ void k_gemm2(const bf16* __restrict__ A, const bf16* __restrict__ B,
                        const float* __restrict__ fq, const float* __restrict__ lamp,
                        float* __restrict__ out) {
    __shared__ alignas(16) bf16 As[64 * 32];
    __shared__ alignas(16) bf16 Bs[128 * 32];
    const int pt = blockIdx.x, ct = blockIdx.y, b = blockIdx.z;
    const int t = threadIdx.x, w = t >> 6, lane = t & 63;
    const int quad = lane >> 4, r15 = lane & 15;
    const int wr = w & 1, wc = w >> 1;
    const bf16* Abase = A + ((size_t)(b * 512 + ct * 64)) * 512;
    const bf16* Bbase = B + ((size_t)(pt * 128)) * 512;
    const int pr = t >> 2;
    const int gc = (t & 3) ^ ((pr >> 1) & 3);
    f32x4 acc[2][4] = {};
    for (int k0 = 0; k0 < 512; k0 += 32) {
        GLL16(Abase + (size_t)pr * 512 + k0 + gc * 8, As + t * 8);
        GLL16(Bbase + (size_t)pr * 512 + k0 + gc * 8, Bs + t * 8);
        GLL16(Bbase + (size_t)(pr + 64) * 512 + k0 + gc * 8, Bs + (t + 256) * 8);
        __syncthreads();
        bf16x8 af[2], bfr[4];
#pragma unroll
        for (int mi = 0; mi < 2; ++mi) {
            int R = wr * 32 + mi * 16 + r15;
            int sc = quad ^ ((R >> 1) & 3);
            af[mi] = *(const bf16x8*)(As + R * 32 + sc * 8);
        }
#pragma unroll
        for (int j = 0; j < 4; ++j) {
            int R = wc * 64 + j * 16 + r15;
            int sc = quad ^ ((R >> 1) & 3);
            bfr[j] = *(const bf16x8*)(Bs + R * 32 + sc * 8);
        }
#pragma unroll
        for (int mi = 0; mi < 2; ++mi)
#pragma unroll
            for (int j = 0; j < 4; ++j)
                acc[mi][j] = __builtin_amdgcn_mfma_f32_16x16x32_bf16(af[mi], bfr[j], acc[mi][j], 0, 0, 0);
        __syncthreads();
    }
    float lam = lamp[0];
#pragma unroll
    for (int mi = 0; mi < 2; ++mi) {
        size_t rowbase = (size_t)(b * 512 + ct * 64 + wr * 32 + mi * 16 + quad * 4);
#pragma unroll
        for (int j = 0; j < 4; ++j)
#pragma unroll
            for (int ii = 0; ii < 4; ++ii) {
                size_t idx = (rowbase + ii) * 1024 + pt * 128 + wc * 64 + j * 16 + r15;
                out[idx] = fq[idx] + lam * acc[mi][j][ii];
            }
    }
}

// K6: z<16: alog[b,p] = sum_d (tbp0+tbp1)[b,d]*fsm[d,p]; z>=16: blog via r
// 4 partial sums for ILP.
__global__ void k_logits(const float* __restrict__ tbp, const float* __restrict__ r,
                         const float* __restrict__ wsq, const float* __restrict__ wsk,
                         const float* __restrict__ fsm32, float* __restrict__ alog,
                         float* __restrict__ blog) {
    int z = blockIdx.y, pq = blockIdx.x * 256 + threadIdx.x;
    if (z < 16) {
        const float* t0 = tbp + z * 512;
        const float* t1 = tbp + (16 + z) * 512;
        float s0 = 0.f, s1 = 0.f, s2 = 0.f, s3 = 0.f;
#pragma unroll 2
        for (int d = 0; d < 512; d += 4) {
            s0 += (t0[d] + t1[d]) * fsm32[(size_t)d * 1024 + pq];
            s1 += (t0[d + 1] + t1[d + 1]) * fsm32[(size_t)(d + 1) * 1024 + pq];
            s2 += (t0[d + 2] + t1[d + 2]) * fsm32[(size_t)(d + 2) * 1024 + pq];
            s3 += (t0[d + 3] + t1[d + 3]) * fsm32[(size_t)(d + 3) * 1024 + pq];
        }
        alog[z * 1024 + pq] = (s0 + s1) + (s2 + s3);
    } else {
        int b = z - 16;
        const float* rb = r + b * 512;
        float s0 = 0.f, s1 = 0.f, s2 = 0.f, s3 = 0.f;
#pragma unroll 2
        for (int c = 0; c < 512; c += 4) {
            s0 += rb[c] * wsq[c] * wsk[c] * (1.f / 256.f) * fsm32[(size_t)c * 1024 + pq];
            s1 += rb[c + 1] * wsq[c + 1] * wsk[c + 1] * (1.f / 256.f) * fsm32[(size_t)(c + 1) * 1024 + pq];
            s2 += rb[c + 2] * wsq[c + 2] * wsk[c + 2] * (1.f / 256.f) * fsm32[(size_t)(c + 2) * 1024 + pq];
            s3 += rb[c + 3] * wsq[c + 3] * wsk[c + 3] * (1.f / 256.f) * fsm32[(size_t)(c + 3) * 1024 + pq];
        }
        blog[b * 1024 + pq] = (s0 + s1) + (s2 + s3);
    }
}

// K7: z<16: alpha softmax -> out; z>=16: beta softmax -> ws
__global__ void k_softmax_rows(const float* __restrict__ alog, const float* __restrict__ blog,
                               float* __restrict__ alpha_out, float* __restrict__ beta) {
    int z = blockIdx.x;
    int t = threadIdx.x;
    int w = t >> 6, lane = t & 63;
    const float* src = (z < 16) ? (alog + (size_t)z * 1024) : (blog + (size_t)(z - 16) * 1024);
    float v[4];
    float mx = -3.4e38f;
#pragma unroll
    for (int j = 0; j < 4; ++j) {
        v[j] = src[t + 256 * j];
        mx = fmaxf(mx, v[j]);
    }
    __shared__ float red[4];
    float wm = wave_reduce_max(mx);
    if (lane == 0) red[w] = wm;
    __syncthreads();
    mx = fmaxf(fmaxf(red[0], red[1]), fmaxf(red[2], red[3]));
    float s = 0.f;
#pragma unroll
    for (int j = 0; j < 4; ++j) {
        v[j] = __expf(v[j] - mx);
        s += v[j];
    }
    __syncthreads();
    float ws_ = wave_reduce_sum(s);
    if (lane == 0) red[w] = ws_;
    __syncthreads();
    s = red[0] + red[1] + red[2] + red[3];
    float inv = 1.f / s;
    if (z < 16) {
#pragma unroll
        for (int j = 0; j < 4; ++j) alpha_out[(size_t)z * 1024 + t + 256 * j] = v[j] * inv;
    } else {
#pragma unroll
        for (int j = 0; j < 4; ++j) beta[(size_t)(z - 16) * 1024 + t + 256 * j] = v[j] * inv;
    }
}

// K8: beta_mean broadcast
__global__ void k_betamean(const float* __restrict__ beta, float* __restrict__ out) {
    int q = blockIdx.x * 256 + threadIdx.x;
    float s = 0.f;
#pragma unroll
    for (int b = 0; b < 16; ++b) s += beta[b * 1024 + q];
    float val = s * (1.f / 16.f);
#pragma unroll
    for (int si = 0; si < 16; ++si) out[(size_t)si * 1024 + q] = val;
}

extern "C" void kernel_launch(void* const* d_in, const int* in_sizes, int n_in,
                              void* d_out, int out_size, void* d_ws, size_t ws_size,
                              hipStream_t stream) {
    const float* f_q = (const float*)d_in[0];
    const float* f_s = (const float*)d_in[1];
    const float* w_cca_q = (const float*)d_in[2];
    const float* w_cca_k = (const float*)d_in[3];
    const float* w_cca_v = (const float*)d_in[4];
    const float* w_sca_q = (const float*)d_in[5];
    const float* w_sca_k = (const float*)d_in[6];
    const float* lamp = (const float*)d_in[7];

    char* ws = (char*)d_ws;
    float* fsm32 = (float*)(ws + 0);             //  2 MB   [512,1024]
    bf16* fsm16 = (bf16*)(ws + 2097152);         //  1 MB
    bf16* fsmT = (bf16*)(ws + 3145728);          //  1 MB   [1024,512]
    float* G = (float*)(ws + 4194304);           // 16 MB   [16,512,512]
    bf16* Acw = (bf16*)(ws + 20971520);          //  8 MB   [16,512,512]
    bf16* fq16 = (bf16*)(ws + 29360128);         // 16.8 MB [16,512,1024]
    float* rm = (float*)(ws + 46137344);         //  2 KB
    float* u = (float*)(ws + 46139392);          //  2 KB
    float* r = (float*)(ws + 46141440);          // 32 KB   [16,512]
    float* tbp = (float*)(ws + 46174208);        // 64 KB   [32,512]
    float* alog = (float*)(ws + 46239744);       // 64 KB
    float* blog = (float*)(ws + 46305280);       // 64 KB
    float* beta = (float*)(ws + 46370816);       // 64 KB

    float* out_fq = (float*)d_out;
    float* out_alpha = out_fq + 8388608;
    float* out_bmean = out_fq + 8404992;

    k_prep<<<dim3(32, 16), 256, 0, stream>>>(f_s, f_q, fsm32, fsm16, fsmT, fq16);
    k_u<<<512, 256, 0, stream>>>(fsm32, w_sca_q, w_sca_k, u, rm);
    k_gemm1<<<dim3(4, 8, 16), 256, 0, stream>>>(fq16, fsm16, G);
    k_softmax_ac<<<2048, 256, 0, stream>>>(G, w_cca_q, w_cca_k, w_cca_v, rm, Acw, r);
    k_t<<<dim3(2, 16, 2), 256, 0, stream>>>(Acw, u, tbp);
    k_gemm2<<<dim3(8, 8, 16), 256, 0, stream>>>(Acw, fsmT, f_q, lamp, out_fq);
    k_logits<<<dim3(4, 32), 256, 0, stream>>>(tbp, r, w_sca_q, w_sca_k, fsm32, alog, blog);
    k_softmax_rows<<<32, 256, 0, stream>>>(alog, blog, out_alpha, beta);
    k_betamean<<<4, 256, 0, stream>>>(beta, out_bmean);
}

// Round 2
// 181.755 us; speedup vs baseline: 1.1230x; 1.1145x over previous
//
#include <hip/hip_runtime.h>

typedef __bf16 bf16;
typedef __bf16 bf16x4 __attribute__((ext_vector_type(4)));
typedef __bf16 bf16x8 __attribute__((ext_vector_type(8)));
typedef float f32x4 __attribute__((ext_vector_type(4)));

// B_Nq = B_Ns = 16, C = 512, P = 1024, TAU*C = 256. I/O fp32; GEMMs bf16 MFMA.

#define GLL16(g, l)                                                             \
    __builtin_amdgcn_global_load_lds((const __attribute__((address_space(1))) void*)(g), \
                                     (__attribute__((address_space(3))) void*)(l), 16, 0, 0)

__device__ inline float wave_reduce_sum(float v) {
#pragma unroll
    for (int m = 32; m >= 1; m >>= 1) v += __shfl_xor(v, m, 64);
    return v;
}
__device__ inline float wave_reduce_max(float v) {
#pragma unroll
    for (int m = 32; m >= 1; m >>= 1) v = fmaxf(v, __shfl_xor(v, m, 64));
    return v;
}

// K0: fused prep — fs_mean (fp32+bf16), fs_mean transpose (bf16), f_q cvt to bf16.
// float4 loads on the f_s stream (33.5 MB — the big one).
// grid (32 p-tiles, 16 c-tiles), block 256.
__global__ void k_prep(const float* __restrict__ fs, const float* __restrict__ fq,
                       float* __restrict__ fsm32, bf16* __restrict__ fsm16,
                       bf16* __restrict__ fsmT, bf16* __restrict__ fq16) {
    __shared__ bf16 tile[32][33];
    int bx = blockIdx.x, by = blockIdx.y;
    int p0 = bx * 32, c0 = by * 32;
    int t = threadIdx.x;
    int cy = t >> 3, px = (t & 7) * 4;
    size_t off = (size_t)(c0 + cy) * 1024 + p0 + px;
    float4 s = {0.f, 0.f, 0.f, 0.f};
#pragma unroll
    for (int b = 0; b < 16; ++b) {
        float4 v = *(const float4*)(fs + (size_t)b * 524288 + off);
        s.x += v.x; s.y += v.y; s.z += v.z; s.w += v.w;
    }
    s.x *= (1.f / 16.f); s.y *= (1.f / 16.f); s.z *= (1.f / 16.f); s.w *= (1.f / 16.f);
    *(float4*)(fsm32 + off) = s;
    bf16x4 h4 = {(bf16)s.x, (bf16)s.y, (bf16)s.z, (bf16)s.w};
    *(bf16x4*)(fsm16 + off) = h4;
    tile[cy][px] = h4[0];
    tile[cy][px + 1] = h4[1];
    tile[cy][px + 2] = h4[2];
    tile[cy][px + 3] = h4[3];
    __syncthreads();
    int tx = t & 31, ty = t >> 5;
#pragma unroll
    for (int i = 0; i < 4; ++i)
        fsmT[(size_t)(p0 + ty + 8 * i) * 512 + c0 + tx] = tile[tx][ty + 8 * i];
    // f_q fp32 -> bf16, 16384 floats per block
    int blk = by * 32 + bx;
    const float4* f4 = (const float4*)fq;
#pragma unroll
    for (int i = 0; i < 16; ++i) {
        int idx = blk * 4096 + i * 256 + t;  // float4 index
        float4 v = f4[idx];
        bf16x4 q4 = {(bf16)v.x, (bf16)v.y, (bf16)v.z, (bf16)v.w};
        *(bf16x4*)(fq16 + (size_t)idx * 4) = q4;
    }
}

// K1: rm[c] = rowmean(fs_mean[c,:]); u[c] = wsq[c]*wsk[c]*rm[c]/256
__global__ void k_u(const float* __restrict__ fsm32, const float* __restrict__ wsq,
                    const float* __restrict__ wsk, float* __restrict__ u,
                    float* __restrict__ rm) {
    int c = blockIdx.x;
    int t = threadIdx.x;
    float s = 0.f;
#pragma unroll
    for (int j = 0; j < 4; ++j) s += fsm32[(size_t)c * 1024 + t + 256 * j];
    s = wave_reduce_sum(s);
    __shared__ float red[4];
    int w = t >> 6, lane = t & 63;
    if (lane == 0) red[w] = s;
    __syncthreads();
    if (t == 0) {
        float rmv = (red[0] + red[1] + red[2] + red[3]) * (1.f / 1024.f);
        rm[c] = rmv;
        u[c] = wsq[c] * wsk[c] * rmv * (1.f / 256.f);
    }
}

// K2: G[b,c,d] = sum_p fq16[b,c,p]*fsm16[d,p] — 64(c)x128(d) tile, BK=64,
// 2-phase double-buffered pipeline (prefetch next K-tile before compute; single
// vmcnt(0)+barrier per tile). XOR-swizzled LDS (chunk ^= row&7, 8x16B chunks/row)
// via pre-swizzled global source (global_load_lds writes linearly).
// grid (4 dt, 8 ct, 16 b), 48 KB LDS -> 3 blocks/CU.
__global__ void k_gemm1(const bf16* __restrict__ A, const bf16* __restrict__ B,
                        float* __restrict__ G) {
    __shared__ alignas(16) bf16 As[2][64 * 64];
    __shared__ alignas(16) bf16 Bs[2][128 * 64];
    const int dt = blockIdx.x, ct = blockIdx.y, b = blockIdx.z;
    const int t = threadIdx.x, w = t >> 6, lane = t & 63;
    const int quad = lane >> 4, r15 = lane & 15;
    const int wr = w & 1, wc = w >> 1;
    const bf16* Abase = A + ((size_t)(b * 512 + ct * 64)) * 1024;
    const bf16* Bbase = B + ((size_t)(dt * 128)) * 1024;
    const int srow = t >> 3, schunk = t & 7;
    f32x4 acc[2][4] = {};
    auto STAGE = [&](int buf, int k0) {
#pragma unroll
        for (int i = 0; i < 2; ++i) {
            int row = i * 32 + srow;
            int gchunk = schunk ^ (row & 7);
            GLL16(Abase + (size_t)row * 1024 + k0 + gchunk * 8, &As[buf][i * 2048 + t * 8]);
        }
#pragma unroll
        for (int i = 0; i < 4; ++i) {
            int row = i * 32 + srow;
            int gchunk = schunk ^ (row & 7);
            GLL16(Bbase + (size_t)row * 1024 + k0 + gchunk * 8, &Bs[buf][i * 2048 + t * 8]);
        }
    };
    STAGE(0, 0);
    __syncthreads();
    int cur = 0;
    for (int step = 0; step < 16; ++step) {
        if (step < 15) STAGE(cur ^ 1, (step + 1) * 64);
#pragma unroll
        for (int ks = 0; ks < 2; ++ks) {
            bf16x8 af[2], bfr[4];
#pragma unroll
            for (int mi = 0; mi < 2; ++mi) {
                int R = wr * 32 + mi * 16 + r15;
                int c = ks * 4 + quad;
                af[mi] = *(const bf16x8*)(&As[cur][R * 64 + ((c ^ (R & 7)) * 8)]);
            }
#pragma unroll
            for (int j = 0; j < 4; ++j) {
                int R = wc * 64 + j * 16 + r15;
                int c = ks * 4 + quad;
                bfr[j] = *(const bf16x8*)(&Bs[cur][R * 64 + ((c ^ (R & 7)) * 8)]);
            }
#pragma unroll
            for (int mi = 0; mi < 2; ++mi)
#pragma unroll
                for (int j = 0; j < 4; ++j)
                    acc[mi][j] = __builtin_amdgcn_mfma_f32_16x16x32_bf16(af[mi], bfr[j], acc[mi][j], 0, 0, 0);
        }
        __syncthreads();
        cur ^= 1;
    }
#pragma unroll
    for (int mi = 0; mi < 2; ++mi) {
        float* g = G + ((size_t)(b * 512 + ct * 64 + wr * 32 + mi * 16 + quad * 4)) * 512 +
                   dt * 128 + wc * 64 + r15;
#pragma unroll
        for (int j = 0; j < 4; ++j)
#pragma unroll
            for (int ii = 0; ii < 4; ++ii)
                g[(size_t)ii * 512 + j * 16] = acc[mi][j][ii];
    }
}

// K3: row softmax of G*wq[c]*wk[d]/P -> Acw (folds wv); r[b,c] = sum_d Acw*rm[d].
// Also zero-inits alog+blog (32K contiguous floats) for the atomic accumulators.
__global__ void k_softmax_ac(const float* __restrict__ G, const float* __restrict__ wq,
                             const float* __restrict__ wk, const float* __restrict__ wv,
                             const float* __restrict__ rm, bf16* __restrict__ Acw,
                             float* __restrict__ r, float* __restrict__ zbuf) {
    if (blockIdx.x < 128) zbuf[blockIdx.x * 256 + threadIdx.x] = 0.f;
    int row = blockIdx.x * 4 + (threadIdx.x >> 6);  // b*512 + c
    int lane = threadIdx.x & 63;
    int c = row & 511;
    const float* g = G + (size_t)row * 512;
    float sc = wq[c] * (1.f / 1024.f);
    float v[8];
    float mx = -3.4e38f;
#pragma unroll
    for (int j = 0; j < 8; ++j) {
        int d = lane + 64 * j;
        v[j] = g[d] * sc * wk[d];
        mx = fmaxf(mx, v[j]);
    }
    mx = wave_reduce_max(mx);
    float sum = 0.f;
#pragma unroll
    for (int j = 0; j < 8; ++j) {
        v[j] = __expf(v[j] - mx);
        sum += v[j];
    }
    sum = wave_reduce_sum(sum);
    float inv = 1.f / sum;
    bf16* o = Acw + (size_t)row * 512;
    float rsum = 0.f;
#pragma unroll
    for (int j = 0; j < 8; ++j) {
        int d = lane + 64 * j;
        float aw = v[j] * inv * wv[d];
        o[d] = (bf16)aw;
        rsum += aw * rm[d];
    }
    rsum = wave_reduce_sum(rsum);
    if (lane == 0) r[row] = rsum;
}

// K5: out[b,c,p] = fq + lam*CP; CP[b,c,p] = sum_d Acw[b,c,d]*fsmT[p,d].
// Same 2-phase BK=64 pipeline as K2. Epilogue also accumulates
// alog[b,p] += sum_{c in tile} u[c]*CP[b,c,p] (cross-quad shfl reduce + atomicAdd),
// replacing the old k_t + alog-GEMM. grid (8 pt, 8 ct, 16 b).
__global__ void k_gemm2(const bf16* __restrict__ A, const bf16* __restrict__ B,
                        const float* __restrict__ fq, const float* __restrict__ lamp,
                        const float* __restrict__ u, float* __restrict__ out,
                        float* __restrict__ alog) {
    __shared__ alignas(16) bf16 As[2][64 * 64];
    __shared__ alignas(16) bf16 Bs[2][128 * 64];
    const int pt = blockIdx.x, ct = blockIdx.y, b = blockIdx.z;
    const int t = threadIdx.x, w = t >> 6, lane = t & 63;
    const int quad = lane >> 4, r15 = lane & 15;
    const int wr = w & 1, wc = w >> 1;
    const bf16* Abase = A + ((size_t)(b * 512 + ct * 64)) * 512;
    const bf16* Bbase = B + ((size_t)(pt * 128)) * 512;
    const int srow = t >> 3, schunk = t & 7;
    f32x4 acc[2][4] = {};
    auto STAGE = [&](int buf, int k0) {
#pragma unroll
        for (int i = 0; i < 2; ++i) {
            int row = i * 32 + srow;
            int gchunk = schunk ^ (row & 7);
            GLL16(Abase + (size_t)row * 512 + k0 + gchunk * 8, &As[buf][i * 2048 + t * 8]);
        }
#pragma unroll
        for (int i = 0; i < 4; ++i) {
            int row = i * 32 + srow;
            int gchunk = schunk ^ (row & 7);
            GLL16(Bbase + (size_t)row * 512 + k0 + gchunk * 8, &Bs[buf][i * 2048 + t * 8]);
        }
    };
    STAGE(0, 0);
    __syncthreads();
    int cur = 0;
    for (int step = 0; step < 8; ++step) {
        if (step < 7) STAGE(cur ^ 1, (step + 1) * 64);
#pragma unroll
        for (int ks = 0; ks < 2; ++ks) {
            bf16x8 af[2], bfr[4];
#pragma unroll
            for (int mi = 0; mi < 2; ++mi) {
                int R = wr * 32 + mi * 16 + r15;
                int c = ks * 4 + quad;
                af[mi] = *(const bf16x8*)(&As[cur][R * 64 + ((c ^ (R & 7)) * 8)]);
            }
#pragma unroll
            for (int j = 0; j < 4; ++j) {
                int R = wc * 64 + j * 16 + r15;
                int c = ks * 4 + quad;
                bfr[j] = *(const bf16x8*)(&Bs[cur][R * 64 + ((c ^ (R & 7)) * 8)]);
            }
#pragma unroll
            for (int mi = 0; mi < 2; ++mi)
#pragma unroll
                for (int j = 0; j < 4; ++j)
                    acc[mi][j] = __builtin_amdgcn_mfma_f32_16x16x32_bf16(af[mi], bfr[j], acc[mi][j], 0, 0, 0);
        }
        __syncthreads();
        cur ^= 1;
    }
    float lam = lamp[0];
#pragma unroll
    for (int mi = 0; mi < 2; ++mi) {
        size_t rowbase = (size_t)(b * 512 + ct * 64 + wr * 32 + mi * 16 + quad * 4);
#pragma unroll
        for (int j = 0; j < 4; ++j)
#pragma unroll
            for (int ii = 0; ii < 4; ++ii) {
                size_t idx = (rowbase + ii) * 1024 + pt * 128 + wc * 64 + j * 16 + r15;
                out[idx] = fq[idx] + lam * acc[mi][j][ii];
            }
    }
    // u-weighted row reduction -> alog partial
    float uv[2][4];
#pragma unroll
    for (int mi = 0; mi < 2; ++mi)
#pragma unroll
        for (int ii = 0; ii < 4; ++ii)
            uv[mi][ii] = u[ct * 64 + wr * 32 + mi * 16 + quad * 4 + ii];
#pragma unroll
    for (int j = 0; j < 4; ++j) {
        float pv = 0.f;
#pragma unroll
        for (int mi = 0; mi < 2; ++mi)
#pragma unroll
            for (int ii = 0; ii < 4; ++ii)
                pv += uv[mi][ii] * acc[mi][j][ii];
        pv += __shfl_xor(pv, 16, 64);
        pv += __shfl_xor(pv, 32, 64);
        if (lane < 16)
            atomicAdd(alog + (size_t)b * 1024 + pt * 128 + wc * 64 + j * 16 + r15, pv);
    }
}

// K6: blog[b,q] += sum_{c chunk} r[b,c]*wsq[c]*wsk[c]/256 * fsm32[c,q]
// grid (4 pq, 16 b, 4 c-chunks), atomicAdd into zero-inited blog.
__global__ void k_blog(const float* __restrict__ r, const float* __restrict__ wsq,
                       const float* __restrict__ wsk, const float* __restrict__ fsm32,
                       float* __restrict__ blog) {
    int pq = blockIdx.x * 256 + threadIdx.x;
    int b = blockIdx.y;
    int c0 = blockIdx.z * 128;
    const float* rb = r + b * 512;
    float s0 = 0.f, s1 = 0.f, s2 = 0.f, s3 = 0.f;
#pragma unroll 4
    for (int c = c0; c < c0 + 128; c += 4) {
        s0 += rb[c] * wsq[c] * wsk[c] * fsm32[(size_t)c * 1024 + pq];
        s1 += rb[c + 1] * wsq[c + 1] * wsk[c + 1] * fsm32[(size_t)(c + 1) * 1024 + pq];
        s2 += rb[c + 2] * wsq[c + 2] * wsk[c + 2] * fsm32[(size_t)(c + 2) * 1024 + pq];
        s3 += rb[c + 3] * wsq[c + 3] * wsk[c + 3] * fsm32[(size_t)(c + 3) * 1024 + pq];
    }
    atomicAdd(&blog[(size_t)b * 1024 + pq], ((s0 + s1) + (s2 + s3)) * (1.f / 256.f));
}

// K7: z<16: alpha softmax -> out; z>=16: beta softmax -> ws
__global__ void k_softmax_rows(const float* __restrict__ alog, const float* __restrict__ blog,
                               float* __restrict__ alpha_out, float* __restrict__ beta) {
    int z = blockIdx.x;
    int t = threadIdx.x;
    int w = t >> 6, lane = t & 63;
    const float* src = (z < 16) ? (alog + (size_t)z * 1024) : (blog + (size_t)(z - 16) * 1024);
    float v[4];
    float mx = -3.4e38f;
#pragma unroll
    for (int j = 0; j < 4; ++j) {
        v[j] = src[t + 256 * j];
        mx = fmaxf(mx, v[j]);
    }
    __shared__ float red[4];
    float wm = wave_reduce_max(mx);
    if (lane == 0) red[w] = wm;
    __syncthreads();
    mx = fmaxf(fmaxf(red[0], red[1]), fmaxf(red[2], red[3]));
    float s = 0.f;
#pragma unroll
    for (int j = 0; j < 4; ++j) {
        v[j] = __expf(v[j] - mx);
        s += v[j];
    }
    __syncthreads();
    float ws_ = wave_reduce_sum(s);
    if (lane == 0) red[w] = ws_;
    __syncthreads();
    s = red[0] + red[1] + red[2] + red[3];
    float inv = 1.f / s;
    if (z < 16) {
#pragma unroll
        for (int j = 0; j < 4; ++j) alpha_out[(size_t)z * 1024 + t + 256 * j] = v[j] * inv;
    } else {
#pragma unroll
        for (int j = 0; j < 4; ++j) beta[(size_t)(z - 16) * 1024 + t + 256 * j] = v[j] * inv;
    }
}

// K8: beta_mean broadcast
__global__ void k_betamean(const float* __restrict__ beta, float* __restrict__ out) {
    int q = blockIdx.x * 256 + threadIdx.x;
    float s = 0.f;
#pragma unroll
    for (int b = 0; b < 16; ++b) s += beta[b * 1024 + q];
    float val = s * (1.f / 16.f);
#pragma unroll
    for (int si = 0; si < 16; ++si) out[(size_t)si * 1024 + q] = val;
}

extern "C" void kernel_launch(void* const* d_in, const int* in_sizes, int n_in,
                              void* d_out, int out_size, void* d_ws, size_t ws_size,
                              hipStream_t stream) {
    const float* f_q = (const float*)d_in[0];
    const float* f_s = (const float*)d_in[1];
    const float* w_cca_q = (const float*)d_in[2];
    const float* w_cca_k = (const float*)d_in[3];
    const float* w_cca_v = (const float*)d_in[4];
    const float* w_sca_q = (const float*)d_in[5];
    const float* w_sca_k = (const float*)d_in[6];
    const float* lamp = (const float*)d_in[7];

    char* ws = (char*)d_ws;
    float* fsm32 = (float*)(ws + 0);             //  2 MB   [512,1024]
    bf16* fsm16 = (bf16*)(ws + 2097152);         //  1 MB
    bf16* fsmT = (bf16*)(ws + 3145728);          //  1 MB   [1024,512]
    float* G = (float*)(ws + 4194304);           // 16 MB   [16,512,512]
    bf16* Acw = (bf16*)(ws + 20971520);          //  8 MB   [16,512,512]
    bf16* fq16 = (bf16*)(ws + 29360128);         // 16.8 MB [16,512,1024]
    float* rm = (float*)(ws + 46137344);         //  2 KB
    float* u = (float*)(ws + 46139392);          //  2 KB
    float* r = (float*)(ws + 46141440);          // 32 KB   [16,512]
    float* alog = (float*)(ws + 46239744);       // 64 KB  (contiguous with blog)
    float* blog = (float*)(ws + 46305280);       // 64 KB
    float* beta = (float*)(ws + 46370816);       // 64 KB

    float* out_fq = (float*)d_out;
    float* out_alpha = out_fq + 8388608;
    float* out_bmean = out_fq + 8404992;

    k_prep<<<dim3(32, 16), 256, 0, stream>>>(f_s, f_q, fsm32, fsm16, fsmT, fq16);
    k_u<<<512, 256, 0, stream>>>(fsm32, w_sca_q, w_sca_k, u, rm);
    k_gemm1<<<dim3(4, 8, 16), 256, 0, stream>>>(fq16, fsm16, G);
    k_softmax_ac<<<2048, 256, 0, stream>>>(G, w_cca_q, w_cca_k, w_cca_v, rm, Acw, r, alog);
    k_gemm2<<<dim3(8, 8, 16), 256, 0, stream>>>(Acw, fsmT, f_q, lamp, u, out_fq, alog);
    k_blog<<<dim3(4, 16, 4), 256, 0, stream>>>(r, w_sca_q, w_sca_k, fsm32, blog);
    k_softmax_rows<<<32, 256, 0, stream>>>(alog, blog, out_alpha, beta);
    k_betamean<<<4, 256, 0, stream>>>(beta, out_bmean);
}